// Round 1
// baseline (139.461 us; speedup 1.0000x reference)
//
#include <hip/hip_runtime.h>

// Problem constants (fixed by the reference's setup_inputs)
#define B_   2
#define V_   4
#define C_   32
#define HW_  4096     // 64*64 feature map
#define D_   64
#define P_   (D_*D_*D_)   // 262144 voxels
#define SCL_ (64.0f/255.0f)

// ---------------------------------------------------------------------------
// Transpose features [B,V,C,H,W] -> [B*V, H*W, C]  (channels contiguous per
// pixel so the bilinear gather becomes 8x float4 per corner).
// One block per (bv, 64-pixel tile): stages a 32c x 64hw tile through LDS.
// ---------------------------------------------------------------------------
__global__ __launch_bounds__(256) void tx_kernel(const float* __restrict__ in,
                                                 float* __restrict__ out) {
    __shared__ float tile[32][65];   // +1 pad: conflict-free both phases
    const int bv  = blockIdx.x >> 6;         // 64 tiles per bv
    const int hw0 = (blockIdx.x & 63) << 6;
    const int t   = threadIdx.x;
    const float* src = in + (size_t)bv * C_ * HW_ + hw0;
#pragma unroll
    for (int i = 0; i < 8; ++i) {            // 2048 elems, coalesced on hw
        int e = t + (i << 8);
        tile[e >> 6][e & 63] = src[(e >> 6) * HW_ + (e & 63)];
    }
    __syncthreads();
    float* dst = out + ((size_t)bv * HW_ + hw0) * C_;
#pragma unroll
    for (int i = 0; i < 8; ++i) {            // fully contiguous 2048-float span
        int e = t + (i << 8);
        dst[e] = tile[e & 31][e >> 5];
    }
}

// ---------------------------------------------------------------------------
// Main kernel: one thread per (b, voxel). Projects into each of 4 views,
// bilinear-gathers 32 channels, averages, writes out[b][c][p] (coalesced).
// TX=true  : feat is [BV][HW][C]  (transposed, float4 gathers)
// TX=false : feat is [BV][C][HW]  (native, scalar gathers) — ws fallback
// ---------------------------------------------------------------------------
template <bool TX>
__global__ __launch_bounds__(256) void vol_kernel(
    const float* __restrict__ feat,
    const float* __restrict__ Rm,    // [B][V][3][3]
    const float* __restrict__ Tm,    // [B][V][3]
    const float* __restrict__ Km,    // [B][V][3][3]
    const float* __restrict__ root,  // [B][3]
    float* __restrict__ out)         // [B][C][P]
{
    const int b = blockIdx.x >> 10;                       // 1024 blocks per b
    const int p = ((blockIdx.x & 1023) << 8) | threadIdx.x;
    const int xi = p & 63, yi = (p >> 6) & 63, zi = p >> 12;
    const float X = ((float)xi * (1.0f/63.0f) - 0.5f) * 0.2f;
    const float Y = ((float)yi * (1.0f/63.0f) - 0.5f) * 0.2f;
    const float Z = ((float)zi * (1.0f/63.0f) - 0.5f) * 0.2f;

    float acc[C_];
#pragma unroll
    for (int c = 0; c < C_; ++c) acc[c] = 0.0f;

    const float rx = root[b*3+0], ry = root[b*3+1], rz = root[b*3+2];

#pragma unroll
    for (int v = 0; v < V_; ++v) {
        const int bv = b * V_ + v;
        const float* Rb = Rm + bv * 9;
        const float* Tb = Tm + bv * 3;
        const float* Kb = Km + bv * 9;
        const float r00=Rb[0], r01=Rb[1], r02=Rb[2];
        const float r10=Rb[3], r11=Rb[4], r12=Rb[5];
        const float r20=Rb[6], r21=Rb[7], r22=Rb[8];
        // new_T = R @ root + T
        const float t0 = r00*rx + r01*ry + r02*rz + Tb[0];
        const float t1 = r10*rx + r11*ry + r12*rz + Tb[1];
        const float t2 = r20*rx + r21*ry + r22*rz + Tb[2];
        // pts_cam = pts @ R^T + new_T   (einsum 'pj,bvij->bvpi')
        const float xc = r00*X + r01*Y + r02*Z + t0;
        const float yc = r10*X + r11*Y + r12*Z + t1;
        float zc       = r20*X + r21*Y + r22*Z + t2;
        zc = fmaxf(zc, 1e-5f);
        // px = u*64/255 - 0.5 with u = xc*fx/zc + cx  (folded unnormalize)
        const float inv = 1.0f / zc;
        const float px = xc * (Kb[0]*SCL_) * inv + (Kb[2]*SCL_ - 0.5f);
        const float py = yc * (Kb[4]*SCL_) * inv + (Kb[5]*SCL_ - 0.5f);

        const float x0f = floorf(px), y0f = floorf(py);
        const float wx1 = px - x0f, wx0 = 1.0f - wx1;
        const float wy1 = py - y0f, wy0 = 1.0f - wy1;
        const float x1f = x0f + 1.0f, y1f = y0f + 1.0f;
        const float vx0 = (x0f >= 0.0f && x0f <= 63.0f) ? 1.0f : 0.0f;
        const float vx1 = (x1f >= 0.0f && x1f <= 63.0f) ? 1.0f : 0.0f;
        const float vy0 = (y0f >= 0.0f && y0f <= 63.0f) ? 1.0f : 0.0f;
        const float vy1 = (y1f >= 0.0f && y1f <= 63.0f) ? 1.0f : 0.0f;
        const float w00 = wx0*wy0*vx0*vy0, w01 = wx1*wy0*vx1*vy0;
        const float w10 = wx0*wy1*vx0*vy1, w11 = wx1*wy1*vx1*vy1;
        // clip (on float, like jnp.clip then int cast) — no int overflow
        const int x0c = (int)fminf(fmaxf(x0f, 0.0f), 63.0f);
        const int x1c = (int)fminf(fmaxf(x1f, 0.0f), 63.0f);
        const int y0c = (int)fminf(fmaxf(y0f, 0.0f), 63.0f);
        const int y1c = (int)fminf(fmaxf(y1f, 0.0f), 63.0f);

        if constexpr (TX) {
            const float* fb = feat + (size_t)bv * HW_ * C_;
            const float4* q00 = (const float4*)(fb + (size_t)(y0c*64 + x0c) * C_);
            const float4* q01 = (const float4*)(fb + (size_t)(y0c*64 + x1c) * C_);
            const float4* q10 = (const float4*)(fb + (size_t)(y1c*64 + x0c) * C_);
            const float4* q11 = (const float4*)(fb + (size_t)(y1c*64 + x1c) * C_);
#pragma unroll
            for (int i = 0; i < 8; ++i) {
                const float4 a = q00[i], bq = q01[i], cq = q10[i], dq = q11[i];
                acc[4*i+0] += w00*a.x + w01*bq.x + w10*cq.x + w11*dq.x;
                acc[4*i+1] += w00*a.y + w01*bq.y + w10*cq.y + w11*dq.y;
                acc[4*i+2] += w00*a.z + w01*bq.z + w10*cq.z + w11*dq.z;
                acc[4*i+3] += w00*a.w + w01*bq.w + w10*cq.w + w11*dq.w;
            }
        } else {
            const float* fb = feat + (size_t)bv * C_ * HW_;
            const int i00 = y0c*64 + x0c, i01 = y0c*64 + x1c;
            const int i10 = y1c*64 + x0c, i11 = y1c*64 + x1c;
#pragma unroll
            for (int c = 0; c < C_; ++c) {
                const float* f = fb + c * HW_;
                acc[c] += w00*f[i00] + w01*f[i01] + w10*f[i10] + w11*f[i11];
            }
        }
    }

    float* ob = out + (size_t)b * C_ * P_ + p;
#pragma unroll
    for (int c = 0; c < C_; ++c) ob[(size_t)c * P_] = acc[c] * 0.25f;
}

extern "C" void kernel_launch(void* const* d_in, const int* in_sizes, int n_in,
                              void* d_out, int out_size, void* d_ws, size_t ws_size,
                              hipStream_t stream) {
    const float* feat = (const float*)d_in[0];   // [2,4,32,64,64]
    const float* Rm   = (const float*)d_in[1];   // [2,4,3,3]
    const float* Tm   = (const float*)d_in[2];   // [2,4,3]
    const float* Km   = (const float*)d_in[3];   // [2,4,3,3]
    const float* root = (const float*)d_in[4];   // [2,3]
    float* out = (float*)d_out;                  // [2,32,64,64,64]

    const size_t need = (size_t)B_ * V_ * HW_ * C_ * sizeof(float);  // 4 MiB
    if (ws_size >= need) {
        float* ftx = (float*)d_ws;
        tx_kernel<<<B_ * V_ * 64, 256, 0, stream>>>(feat, ftx);
        vol_kernel<true><<<B_ * P_ / 256, 256, 0, stream>>>(ftx, Rm, Tm, Km, root, out);
    } else {
        vol_kernel<false><<<B_ * P_ / 256, 256, 0, stream>>>(feat, Rm, Tm, Km, root, out);
    }
}

// Round 2
// 102.248 us; speedup vs baseline: 1.3639x; 1.3639x over previous
//
#include <hip/hip_runtime.h>

// Problem constants (fixed by the reference's setup_inputs)
#define B_   2
#define V_   4
#define C_   32
#define HW_  4096     // 64*64 feature map
#define D_   64
#define P_   (D_*D_*D_)   // 262144 voxels
#define SCL_ (64.0f/255.0f)

typedef _Float16 half2v __attribute__((ext_vector_type(2)));

// One corner's 16 channels (h-half of a 64B pixel block): 32 B
union Corner { uint4 u[2]; half2v h[8]; };

// ---------------------------------------------------------------------------
// Transpose+convert: fp32 [B,V,C,H,W] -> fp16 [B*V, H*W, C]
// One pixel = 32ch * 2B = 64 B = exactly one cache line.
// ---------------------------------------------------------------------------
__global__ __launch_bounds__(256) void tx_kernel(const float* __restrict__ in,
                                                 unsigned int* __restrict__ out) {
    __shared__ float tile[32][65];   // +1 pad: conflict-free both phases
    const int bv  = blockIdx.x >> 6;         // 64 tiles per bv
    const int hw0 = (blockIdx.x & 63) << 6;
    const int t   = threadIdx.x;
    const float* src = in + (size_t)bv * C_ * HW_ + hw0;
#pragma unroll
    for (int i = 0; i < 8; ++i) {            // 2048 elems, coalesced on hw
        int e = t + (i << 8);
        tile[e >> 6][e & 63] = src[(e >> 6) * HW_ + (e & 63)];
    }
    __syncthreads();
    // pack 2 consecutive channels into one u32; 1024 u32 per tile, contiguous
    unsigned int* dst = out + ((size_t)bv * HW_ + hw0) * (C_ / 2);
#pragma unroll
    for (int i = 0; i < 4; ++i) {
        int idx = t + (i << 8);
        int c  = (idx << 1) & 31;            // even channel
        int hw = idx >> 4;                   // (idx*2) >> 5
        half2v v = { (_Float16)tile[c][hw], (_Float16)tile[c + 1][hw] };
        dst[idx] = *(unsigned int*)&v;
    }
}

// ---------------------------------------------------------------------------
// Main kernel (fp16 path): thread = (voxel, channel-half). Wave = 32 voxels
// x 2 halves -> ~11 distinct 64B lines per gather request, fully used.
// Per-view bilinear in packed fp16 (v_pk_fma_f16), cross-view accum in fp32.
// ---------------------------------------------------------------------------
__global__ __launch_bounds__(256) void vol_kernel(
    const unsigned char* __restrict__ feat,  // fp16 [BV][HW][C] as bytes
    const float* __restrict__ Rm,    // [B][V][3][3]
    const float* __restrict__ Tm,    // [B][V][3]
    const float* __restrict__ Km,    // [B][V][3][3]
    const float* __restrict__ root,  // [B][3]
    float* __restrict__ out)         // [B][C][P]
{
    const int b = blockIdx.x >> 11;                     // 2048 blocks per b
    const int t = threadIdx.x;
    const int h = t & 1;                                // channel half
    const int p = ((blockIdx.x & 2047) << 7) | (t >> 1);
    const int xi = p & 63, yi = (p >> 6) & 63, zi = p >> 12;
    const float X = ((float)xi * (1.0f/63.0f) - 0.5f) * 0.2f;
    const float Y = ((float)yi * (1.0f/63.0f) - 0.5f) * 0.2f;
    const float Z = ((float)zi * (1.0f/63.0f) - 0.5f) * 0.2f;

    float acc[16];
#pragma unroll
    for (int j = 0; j < 16; ++j) acc[j] = 0.0f;

    const float rx = root[b*3+0], ry = root[b*3+1], rz = root[b*3+2];

#pragma unroll
    for (int v = 0; v < V_; ++v) {
        const int bv = b * V_ + v;
        const float* Rb = Rm + bv * 9;
        const float* Tb = Tm + bv * 3;
        const float* Kb = Km + bv * 9;
        const float r00=Rb[0], r01=Rb[1], r02=Rb[2];
        const float r10=Rb[3], r11=Rb[4], r12=Rb[5];
        const float r20=Rb[6], r21=Rb[7], r22=Rb[8];
        const float t0 = r00*rx + r01*ry + r02*rz + Tb[0];
        const float t1 = r10*rx + r11*ry + r12*rz + Tb[1];
        const float t2 = r20*rx + r21*ry + r22*rz + Tb[2];
        const float xc = r00*X + r01*Y + r02*Z + t0;
        const float yc = r10*X + r11*Y + r12*Z + t1;
        float zc       = r20*X + r21*Y + r22*Z + t2;
        zc = fmaxf(zc, 1e-5f);
        const float inv = 1.0f / zc;
        const float px = xc * (Kb[0]*SCL_) * inv + (Kb[2]*SCL_ - 0.5f);
        const float py = yc * (Kb[4]*SCL_) * inv + (Kb[5]*SCL_ - 0.5f);

        const float x0f = floorf(px), y0f = floorf(py);
        const float wx1 = px - x0f, wx0 = 1.0f - wx1;
        const float wy1 = py - y0f, wy0 = 1.0f - wy1;
        const float x1f = x0f + 1.0f, y1f = y0f + 1.0f;
        const float vx0 = (x0f >= 0.0f && x0f <= 63.0f) ? 1.0f : 0.0f;
        const float vx1 = (x1f >= 0.0f && x1f <= 63.0f) ? 1.0f : 0.0f;
        const float vy0 = (y0f >= 0.0f && y0f <= 63.0f) ? 1.0f : 0.0f;
        const float vy1 = (y1f >= 0.0f && y1f <= 63.0f) ? 1.0f : 0.0f;
        // fold the 1/V view-mean into the weights
        const float w00 = wx0*wy0*vx0*vy0*0.25f, w01 = wx1*wy0*vx1*vy0*0.25f;
        const float w10 = wx0*wy1*vx0*vy1*0.25f, w11 = wx1*wy1*vx1*vy1*0.25f;
        const int x0c = (int)fminf(fmaxf(x0f, 0.0f), 63.0f);
        const int x1c = (int)fminf(fmaxf(x1f, 0.0f), 63.0f);
        const int y0c = (int)fminf(fmaxf(y0f, 0.0f), 63.0f);
        const int y1c = (int)fminf(fmaxf(y1f, 0.0f), 63.0f);

        const unsigned char* fb = feat + (size_t)bv * HW_ * 64 + h * 32;
        const Corner c00 = *(const Corner*)(fb + (size_t)(y0c*64 + x0c) * 64);
        const Corner c01 = *(const Corner*)(fb + (size_t)(y0c*64 + x1c) * 64);
        const Corner c10 = *(const Corner*)(fb + (size_t)(y1c*64 + x0c) * 64);
        const Corner c11 = *(const Corner*)(fb + (size_t)(y1c*64 + x1c) * 64);

        const half2v w00h = { (_Float16)w00, (_Float16)w00 };
        const half2v w01h = { (_Float16)w01, (_Float16)w01 };
        const half2v w10h = { (_Float16)w10, (_Float16)w10 };
        const half2v w11h = { (_Float16)w11, (_Float16)w11 };
#pragma unroll
        for (int j = 0; j < 8; ++j) {
            half2v s = c00.h[j] * w00h;
            s += c01.h[j] * w01h;
            s += c10.h[j] * w10h;
            s += c11.h[j] * w11h;
            acc[2*j+0] += (float)s.x;   // cross-view accumulation in fp32
            acc[2*j+1] += (float)s.y;
        }
    }

    float* ob = out + ((size_t)(b * C_) + (h << 4)) * P_ + p;
#pragma unroll
    for (int j = 0; j < 16; ++j)
        __builtin_nontemporal_store(acc[j], ob + (size_t)j * P_);
}

// ---------------------------------------------------------------------------
// Fallback (no workspace): fp32 native-layout scalar gathers.
// ---------------------------------------------------------------------------
__global__ __launch_bounds__(256) void vol_fallback(
    const float* __restrict__ feat,
    const float* __restrict__ Rm, const float* __restrict__ Tm,
    const float* __restrict__ Km, const float* __restrict__ root,
    float* __restrict__ out)
{
    const int b = blockIdx.x >> 10;
    const int p = ((blockIdx.x & 1023) << 8) | threadIdx.x;
    const int xi = p & 63, yi = (p >> 6) & 63, zi = p >> 12;
    const float X = ((float)xi * (1.0f/63.0f) - 0.5f) * 0.2f;
    const float Y = ((float)yi * (1.0f/63.0f) - 0.5f) * 0.2f;
    const float Z = ((float)zi * (1.0f/63.0f) - 0.5f) * 0.2f;
    float acc[C_];
#pragma unroll
    for (int c = 0; c < C_; ++c) acc[c] = 0.0f;
    const float rx = root[b*3+0], ry = root[b*3+1], rz = root[b*3+2];
#pragma unroll
    for (int v = 0; v < V_; ++v) {
        const int bv = b * V_ + v;
        const float* Rb = Rm + bv * 9; const float* Tb = Tm + bv * 3;
        const float* Kb = Km + bv * 9;
        const float r00=Rb[0], r01=Rb[1], r02=Rb[2];
        const float r10=Rb[3], r11=Rb[4], r12=Rb[5];
        const float r20=Rb[6], r21=Rb[7], r22=Rb[8];
        const float t0 = r00*rx + r01*ry + r02*rz + Tb[0];
        const float t1 = r10*rx + r11*ry + r12*rz + Tb[1];
        const float t2 = r20*rx + r21*ry + r22*rz + Tb[2];
        const float xc = r00*X + r01*Y + r02*Z + t0;
        const float yc = r10*X + r11*Y + r12*Z + t1;
        float zc       = r20*X + r21*Y + r22*Z + t2;
        zc = fmaxf(zc, 1e-5f);
        const float inv = 1.0f / zc;
        const float px = xc * (Kb[0]*SCL_) * inv + (Kb[2]*SCL_ - 0.5f);
        const float py = yc * (Kb[4]*SCL_) * inv + (Kb[5]*SCL_ - 0.5f);
        const float x0f = floorf(px), y0f = floorf(py);
        const float wx1 = px - x0f, wx0 = 1.0f - wx1;
        const float wy1 = py - y0f, wy0 = 1.0f - wy1;
        const float x1f = x0f + 1.0f, y1f = y0f + 1.0f;
        const float vx0 = (x0f >= 0.0f && x0f <= 63.0f) ? 1.0f : 0.0f;
        const float vx1 = (x1f >= 0.0f && x1f <= 63.0f) ? 1.0f : 0.0f;
        const float vy0 = (y0f >= 0.0f && y0f <= 63.0f) ? 1.0f : 0.0f;
        const float vy1 = (y1f >= 0.0f && y1f <= 63.0f) ? 1.0f : 0.0f;
        const float w00 = wx0*wy0*vx0*vy0, w01 = wx1*wy0*vx1*vy0;
        const float w10 = wx0*wy1*vx0*vy1, w11 = wx1*wy1*vx1*vy1;
        const int x0c = (int)fminf(fmaxf(x0f, 0.0f), 63.0f);
        const int x1c = (int)fminf(fmaxf(x1f, 0.0f), 63.0f);
        const int y0c = (int)fminf(fmaxf(y0f, 0.0f), 63.0f);
        const int y1c = (int)fminf(fmaxf(y1f, 0.0f), 63.0f);
        const float* fb = feat + (size_t)bv * C_ * HW_;
        const int i00 = y0c*64 + x0c, i01 = y0c*64 + x1c;
        const int i10 = y1c*64 + x0c, i11 = y1c*64 + x1c;
#pragma unroll
        for (int c = 0; c < C_; ++c) {
            const float* f = fb + c * HW_;
            acc[c] += w00*f[i00] + w01*f[i01] + w10*f[i10] + w11*f[i11];
        }
    }
    float* ob = out + (size_t)b * C_ * P_ + p;
#pragma unroll
    for (int c = 0; c < C_; ++c) ob[(size_t)c * P_] = acc[c] * 0.25f;
}

extern "C" void kernel_launch(void* const* d_in, const int* in_sizes, int n_in,
                              void* d_out, int out_size, void* d_ws, size_t ws_size,
                              hipStream_t stream) {
    const float* feat = (const float*)d_in[0];   // [2,4,32,64,64]
    const float* Rm   = (const float*)d_in[1];   // [2,4,3,3]
    const float* Tm   = (const float*)d_in[2];   // [2,4,3]
    const float* Km   = (const float*)d_in[3];   // [2,4,3,3]
    const float* root = (const float*)d_in[4];   // [2,3]
    float* out = (float*)d_out;                  // [2,32,64,64,64]

    const size_t need = (size_t)B_ * V_ * HW_ * C_ * sizeof(_Float16);  // 2 MiB
    if (ws_size >= need) {
        unsigned int* ftx = (unsigned int*)d_ws;
        tx_kernel<<<B_ * V_ * 64, 256, 0, stream>>>(feat, ftx);
        // 256 thr = 128 voxels x 2 channel-halves; grid = 2*2048
        vol_kernel<<<B_ * P_ / 128, 256, 0, stream>>>(
            (const unsigned char*)ftx, Rm, Tm, Km, root, out);
    } else {
        vol_fallback<<<B_ * P_ / 256, 256, 0, stream>>>(feat, Rm, Tm, Km, root, out);
    }
}

// Round 3
// 102.039 us; speedup vs baseline: 1.3667x; 1.0020x over previous
//
#include <hip/hip_runtime.h>

// Problem constants (fixed by the reference's setup_inputs)
#define B_   2
#define V_   4
#define C_   32
#define HW_  4096     // 64*64 feature map
#define D_   64
#define P_   (D_*D_*D_)   // 262144 voxels
#define SCL_ (64.0f/255.0f)

typedef _Float16 half2v __attribute__((ext_vector_type(2)));

// One corner's 8 channels (q-quarter of a 64B pixel block): 16 B = 1 dwordx4
union Corner16 { uint4 u; half2v h[4]; };

// ---------------------------------------------------------------------------
// Transpose+convert: fp32 [B,V,C,H,W] -> fp16 [B*V, H*W, C]
// One pixel = 32ch * 2B = 64 B = exactly one cache line.
// ---------------------------------------------------------------------------
__global__ __launch_bounds__(256) void tx_kernel(const float* __restrict__ in,
                                                 unsigned int* __restrict__ out) {
    __shared__ float tile[32][65];   // +1 pad: conflict-free both phases
    const int bv  = blockIdx.x >> 6;         // 64 tiles per bv
    const int hw0 = (blockIdx.x & 63) << 6;
    const int t   = threadIdx.x;
    const float* src = in + (size_t)bv * C_ * HW_ + hw0;
#pragma unroll
    for (int i = 0; i < 8; ++i) {            // 2048 elems, coalesced on hw
        int e = t + (i << 8);
        tile[e >> 6][e & 63] = src[(e >> 6) * HW_ + (e & 63)];
    }
    __syncthreads();
    // pack 2 consecutive channels into one u32; 1024 u32 per tile, contiguous
    unsigned int* dst = out + ((size_t)bv * HW_ + hw0) * (C_ / 2);
#pragma unroll
    for (int i = 0; i < 4; ++i) {
        int idx = t + (i << 8);
        int c  = (idx << 1) & 31;            // even channel
        int hw = idx >> 4;                   // (idx*2) >> 5
        half2v v = { (_Float16)tile[c][hw], (_Float16)tile[c + 1][hw] };
        dst[idx] = *(unsigned int*)&v;
    }
}

// ---------------------------------------------------------------------------
// Main kernel: thread = (voxel, quarter q). Lane q computes the projection
// for view v=q only; weights+offsets are exchanged across the 4-lane group
// via __shfl (LDS pipe). Each corner gather = one 16B dwordx4; the 4 lanes
// of a voxel consume a full 64B pixel line. Wave = 16 voxels -> ~6 distinct
// lines per corner instruction (1.8x fewer TA line-touches than round 2).
// ---------------------------------------------------------------------------
__global__ __launch_bounds__(256) void vol_kernel(
    const unsigned char* __restrict__ feat,  // fp16 [BV][HW][C] as bytes
    const float* __restrict__ Rm,    // [B][V][3][3]
    const float* __restrict__ Tm,    // [B][V][3]
    const float* __restrict__ Km,    // [B][V][3][3]
    const float* __restrict__ root,  // [B][3]
    float* __restrict__ out)         // [B][C][P]
{
    // cam[v]: r00 r01 r02 t0 | r10 r11 r12 t1 | r20 r21 r22 t2 | fxs fys cxs cys
    // padded to 20 words so the 4 views' float4 reads hit distinct banks
    __shared__ __align__(16) float cam[4][20];

    const int t = threadIdx.x;
    const int q = t & 3;                                // channel quarter = view
    const int b = blockIdx.x >> 12;                     // 4096 blocks per b
    const int p = ((blockIdx.x & 4095) << 6) | (t >> 2);

    if (t < 4) {                                        // one thread per view
        const int bv = b * V_ + t;
        const float* Rb = Rm + bv * 9;
        const float* Tb = Tm + bv * 3;
        const float* Kb = Km + bv * 9;
        const float rx = root[b*3+0], ry = root[b*3+1], rz = root[b*3+2];
        cam[t][0] = Rb[0]; cam[t][1] = Rb[1]; cam[t][2] = Rb[2];
        cam[t][3] = Rb[0]*rx + Rb[1]*ry + Rb[2]*rz + Tb[0];
        cam[t][4] = Rb[3]; cam[t][5] = Rb[4]; cam[t][6] = Rb[5];
        cam[t][7] = Rb[3]*rx + Rb[4]*ry + Rb[5]*rz + Tb[1];
        cam[t][8] = Rb[6]; cam[t][9] = Rb[7]; cam[t][10] = Rb[8];
        cam[t][11] = Rb[6]*rx + Rb[7]*ry + Rb[8]*rz + Tb[2];
        cam[t][12] = Kb[0] * SCL_;          // fx'
        cam[t][13] = Kb[4] * SCL_;          // fy'
        cam[t][14] = Kb[2] * SCL_ - 0.5f;   // cx'
        cam[t][15] = Kb[5] * SCL_ - 0.5f;   // cy'
    }
    __syncthreads();

    const int xi = p & 63, yi = (p >> 6) & 63, zi = p >> 12;
    const float X = ((float)xi * (1.0f/63.0f) - 0.5f) * 0.2f;
    const float Y = ((float)yi * (1.0f/63.0f) - 0.5f) * 0.2f;
    const float Z = ((float)zi * (1.0f/63.0f) - 0.5f) * 0.2f;

    // ---- projection for MY view (v = q) ----
    const float4 cA = *(const float4*)&cam[q][0];
    const float4 cB = *(const float4*)&cam[q][4];
    const float4 cC = *(const float4*)&cam[q][8];
    const float4 cK = *(const float4*)&cam[q][12];
    const float xc = cA.x*X + cA.y*Y + cA.z*Z + cA.w;
    const float yc = cB.x*X + cB.y*Y + cB.z*Z + cB.w;
    float zc       = cC.x*X + cC.y*Y + cC.z*Z + cC.w;
    zc = fmaxf(zc, 1e-5f);
    const float inv = 1.0f / zc;
    const float px = (xc * inv) * cK.x + cK.z;
    const float py = (yc * inv) * cK.y + cK.w;

    const float x0f = floorf(px), y0f = floorf(py);
    const float wx1 = px - x0f, wx0 = 1.0f - wx1;
    const float wy1 = py - y0f, wy0 = 1.0f - wy1;
    const float x1f = x0f + 1.0f, y1f = y0f + 1.0f;
    const float vx0 = (x0f >= 0.0f && x0f <= 63.0f) ? 1.0f : 0.0f;
    const float vx1 = (x1f >= 0.0f && x1f <= 63.0f) ? 1.0f : 0.0f;
    const float vy0 = (y0f >= 0.0f && y0f <= 63.0f) ? 1.0f : 0.0f;
    const float vy1 = (y1f >= 0.0f && y1f <= 63.0f) ? 1.0f : 0.0f;
    // fold the 1/V view-mean into the weights
    const float w00 = wx0*wy0*vx0*vy0*0.25f, w01 = wx1*wy0*vx1*vy0*0.25f;
    const float w10 = wx0*wy1*vx0*vy1*0.25f, w11 = wx1*wy1*vx1*vy1*0.25f;
    const int x0c = (int)fminf(fmaxf(x0f, 0.0f), 63.0f);
    const int x1c = (int)fminf(fmaxf(x1f, 0.0f), 63.0f);
    const int y0c = (int)fminf(fmaxf(y0f, 0.0f), 63.0f);
    const int y1c = (int)fminf(fmaxf(y1f, 0.0f), 63.0f);
    // byte offsets into feat for MY view's bv (receiver adds its own q*16)
    const int bvbase = (b * V_ + q) * HW_;
    const int o00 = (bvbase + y0c*64 + x0c) << 6;
    const int o01 = (bvbase + y0c*64 + x1c) << 6;
    const int o10 = (bvbase + y1c*64 + x0c) << 6;
    const int o11 = (bvbase + y1c*64 + x1c) << 6;

    float acc[8];
#pragma unroll
    for (int j = 0; j < 8; ++j) acc[j] = 0.0f;

    const unsigned char* fb = feat + (q << 4);   // my channel-quarter sub-offset
    const int lane_base = t & ~3;

#pragma unroll
    for (int v = 0; v < V_; ++v) {
        const int src = lane_base | v;
        const float sw00 = __shfl(w00, src), sw01 = __shfl(w01, src);
        const float sw10 = __shfl(w10, src), sw11 = __shfl(w11, src);
        const int so00 = __shfl(o00, src), so01 = __shfl(o01, src);
        const int so10 = __shfl(o10, src), so11 = __shfl(o11, src);

        const Corner16 c00 = *(const Corner16*)(fb + (size_t)(unsigned)so00);
        const Corner16 c01 = *(const Corner16*)(fb + (size_t)(unsigned)so01);
        const Corner16 c10 = *(const Corner16*)(fb + (size_t)(unsigned)so10);
        const Corner16 c11 = *(const Corner16*)(fb + (size_t)(unsigned)so11);

        const half2v h00 = { (_Float16)sw00, (_Float16)sw00 };
        const half2v h01 = { (_Float16)sw01, (_Float16)sw01 };
        const half2v h10 = { (_Float16)sw10, (_Float16)sw10 };
        const half2v h11 = { (_Float16)sw11, (_Float16)sw11 };
#pragma unroll
        for (int j = 0; j < 4; ++j) {
            half2v s = c00.h[j] * h00;
            s += c01.h[j] * h01;
            s += c10.h[j] * h10;
            s += c11.h[j] * h11;
            acc[2*j+0] += (float)s.x;   // cross-view accumulation in fp32
            acc[2*j+1] += (float)s.y;
        }
    }

    float* ob = out + ((size_t)(b * C_) + (q << 3)) * P_ + p;
#pragma unroll
    for (int j = 0; j < 8; ++j)
        __builtin_nontemporal_store(acc[j], ob + (size_t)j * P_);
}

// ---------------------------------------------------------------------------
// Fallback (no workspace): fp32 native-layout scalar gathers.
// ---------------------------------------------------------------------------
__global__ __launch_bounds__(256) void vol_fallback(
    const float* __restrict__ feat,
    const float* __restrict__ Rm, const float* __restrict__ Tm,
    const float* __restrict__ Km, const float* __restrict__ root,
    float* __restrict__ out)
{
    const int b = blockIdx.x >> 10;
    const int p = ((blockIdx.x & 1023) << 8) | threadIdx.x;
    const int xi = p & 63, yi = (p >> 6) & 63, zi = p >> 12;
    const float X = ((float)xi * (1.0f/63.0f) - 0.5f) * 0.2f;
    const float Y = ((float)yi * (1.0f/63.0f) - 0.5f) * 0.2f;
    const float Z = ((float)zi * (1.0f/63.0f) - 0.5f) * 0.2f;
    float acc[C_];
#pragma unroll
    for (int c = 0; c < C_; ++c) acc[c] = 0.0f;
    const float rx = root[b*3+0], ry = root[b*3+1], rz = root[b*3+2];
#pragma unroll
    for (int v = 0; v < V_; ++v) {
        const int bv = b * V_ + v;
        const float* Rb = Rm + bv * 9; const float* Tb = Tm + bv * 3;
        const float* Kb = Km + bv * 9;
        const float r00=Rb[0], r01=Rb[1], r02=Rb[2];
        const float r10=Rb[3], r11=Rb[4], r12=Rb[5];
        const float r20=Rb[6], r21=Rb[7], r22=Rb[8];
        const float t0 = r00*rx + r01*ry + r02*rz + Tb[0];
        const float t1 = r10*rx + r11*ry + r12*rz + Tb[1];
        const float t2 = r20*rx + r21*ry + r22*rz + Tb[2];
        const float xc = r00*X + r01*Y + r02*Z + t0;
        const float yc = r10*X + r11*Y + r12*Z + t1;
        float zc       = r20*X + r21*Y + r22*Z + t2;
        zc = fmaxf(zc, 1e-5f);
        const float inv = 1.0f / zc;
        const float px = xc * (Kb[0]*SCL_) * inv + (Kb[2]*SCL_ - 0.5f);
        const float py = yc * (Kb[4]*SCL_) * inv + (Kb[5]*SCL_ - 0.5f);
        const float x0f = floorf(px), y0f = floorf(py);
        const float wx1 = px - x0f, wx0 = 1.0f - wx1;
        const float wy1 = py - y0f, wy0 = 1.0f - wy1;
        const float x1f = x0f + 1.0f, y1f = y0f + 1.0f;
        const float vx0 = (x0f >= 0.0f && x0f <= 63.0f) ? 1.0f : 0.0f;
        const float vx1 = (x1f >= 0.0f && x1f <= 63.0f) ? 1.0f : 0.0f;
        const float vy0 = (y0f >= 0.0f && y0f <= 63.0f) ? 1.0f : 0.0f;
        const float vy1 = (y1f >= 0.0f && y1f <= 63.0f) ? 1.0f : 0.0f;
        const float w00 = wx0*wy0*vx0*vy0, w01 = wx1*wy0*vx1*vy0;
        const float w10 = wx0*wy1*vx0*vy1, w11 = wx1*wy1*vx1*vy1;
        const int x0c = (int)fminf(fmaxf(x0f, 0.0f), 63.0f);
        const int x1c = (int)fminf(fmaxf(x1f, 0.0f), 63.0f);
        const int y0c = (int)fminf(fmaxf(y0f, 0.0f), 63.0f);
        const int y1c = (int)fminf(fmaxf(y1f, 0.0f), 63.0f);
        const float* fb = feat + (size_t)bv * C_ * HW_;
        const int i00 = y0c*64 + x0c, i01 = y0c*64 + x1c;
        const int i10 = y1c*64 + x0c, i11 = y1c*64 + x1c;
#pragma unroll
        for (int c = 0; c < C_; ++c) {
            const float* f = fb + c * HW_;
            acc[c] += w00*f[i00] + w01*f[i01] + w10*f[i10] + w11*f[i11];
        }
    }
    float* ob = out + (size_t)b * C_ * P_ + p;
#pragma unroll
    for (int c = 0; c < C_; ++c) ob[(size_t)c * P_] = acc[c] * 0.25f;
}

extern "C" void kernel_launch(void* const* d_in, const int* in_sizes, int n_in,
                              void* d_out, int out_size, void* d_ws, size_t ws_size,
                              hipStream_t stream) {
    const float* feat = (const float*)d_in[0];   // [2,4,32,64,64]
    const float* Rm   = (const float*)d_in[1];   // [2,4,3,3]
    const float* Tm   = (const float*)d_in[2];   // [2,4,3]
    const float* Km   = (const float*)d_in[3];   // [2,4,3,3]
    const float* root = (const float*)d_in[4];   // [2,3]
    float* out = (float*)d_out;                  // [2,32,64,64,64]

    const size_t need = (size_t)B_ * V_ * HW_ * C_ * sizeof(_Float16);  // 2 MiB
    if (ws_size >= need) {
        unsigned int* ftx = (unsigned int*)d_ws;
        tx_kernel<<<B_ * V_ * 64, 256, 0, stream>>>(feat, ftx);
        // 256 thr = 64 voxels x 4 channel-quarters; grid = 2*4096
        vol_kernel<<<B_ * P_ / 64, 256, 0, stream>>>(
            (const unsigned char*)ftx, Rm, Tm, Km, root, out);
    } else {
        vol_fallback<<<B_ * P_ / 256, 256, 0, stream>>>(feat, Rm, Tm, Km, root, out);
    }
}